// Round 4
// baseline (117.341 us; speedup 1.0000x reference)
//
#include <hip/hip_runtime.h>
#include <hip/hip_bf16.h>
#include <cmath>
#include <complex>
#include <algorithm>

// ======================================================================
// Host-side exact port of the reference e3nn wigner_3j (unit Frobenius
// norm, real basis, (-1j)^l phase). Computed once, passed by value.
// ======================================================================

typedef std::complex<double> cd;

static double factd(int n) { double r = 1; for (int i = 2; i <= n; ++i) r *= i; return r; }

static double su2_cg(int j1, int m1, int j2, int m2, int j3, int m3) {
    if (m3 != m1 + m2) return 0.0;
    int vmin = std::max(std::max(-j1 + j2 + m3, -j1 + m1), 0);
    int vmax = std::min(std::min(j2 + j3 + m1, j3 - j1 + j2), j3 + m3);
    double C = std::sqrt((2.0 * j3 + 1.0) *
        (factd(j3 + j1 - j2) * factd(j3 - j1 + j2) * factd(j1 + j2 - j3) *
         factd(j3 + m3) * factd(j3 - m3)) /
        (factd(j1 + j2 + j3 + 1) * factd(j1 - m1) * factd(j1 + m1) *
         factd(j2 - m2) * factd(j2 + m2)));
    double S = 0.0;
    for (int v = vmin; v <= vmax; ++v) {
        double sgn = ((v + j2 + m2) & 1) ? -1.0 : 1.0;
        S += sgn * (factd(j2 + j3 + m1 - v) * factd(j1 - m1 + v)) /
             (factd(v) * factd(j3 - j1 + j2 - v) * factd(j3 + m3 - v) *
              factd(v + j1 - j2 - m3));
    }
    return C * S;
}

static void qmat(int l, cd* q) {
    int n = 2 * l + 1;
    for (int i = 0; i < n * n; ++i) q[i] = cd(0, 0);
    const double s = 1.0 / std::sqrt(2.0);
    for (int m = -l; m < 0; ++m) {
        q[(l + m) * n + (l - m)] = cd(s, 0);
        q[(l + m) * n + (l + m)] = cd(0, -s);
    }
    q[l * n + l] = cd(1, 0);
    for (int m = 1; m <= l; ++m) {
        double sg = (m & 1) ? -1.0 : 1.0;
        q[(l + m) * n + (l + m)] = cd(sg * s, 0);
        q[(l + m) * n + (l - m)] = cd(0, sg * s);
    }
    cd ph(1, 0);
    for (int t = 0; t < l; ++t) ph *= cd(0, -1);
    for (int i = 0; i < n * n; ++i) q[i] *= ph;
}

static void wigner3j_dense(int l1, int l2, int l3, double* outp) {
    int n1 = 2 * l1 + 1, n2 = 2 * l2 + 1, n3 = 2 * l3 + 1;
    double cg[125];
    for (int i = 0; i < n1 * n2 * n3; ++i) cg[i] = 0.0;
    for (int m1 = -l1; m1 <= l1; ++m1)
        for (int m2 = -l2; m2 <= l2; ++m2) {
            int m3 = m1 + m2;
            if (std::abs(m3) <= l3)
                cg[((l1 + m1) * n2 + (l2 + m2)) * n3 + (l3 + m3)] =
                    su2_cg(l1, m1, l2, m2, l3, m3);
        }
    cd q1[25], q2[25], q3[25];
    qmat(l1, q1); qmat(l2, q2); qmat(l3, q3);
    double norm2 = 0.0;
    for (int j = 0; j < n1; ++j)
        for (int l = 0; l < n2; ++l)
            for (int m = 0; m < n3; ++m) {
                cd sum(0, 0);
                for (int i = 0; i < n1; ++i)
                    for (int k = 0; k < n2; ++k)
                        for (int n = 0; n < n3; ++n) {
                            double g = cg[(i * n2 + k) * n3 + n];
                            if (g != 0.0)
                                sum += q1[i * n1 + j] * q2[k * n2 + l] *
                                       std::conj(q3[n * n3 + m]) * g;
                        }
                outp[(j * n2 + l) * n3 + m] = sum.real();
                norm2 += sum.real() * sum.real();
            }
    double inv = 1.0 / std::sqrt(norm2);
    for (int t = 0; t < n1 * n2 * n3; ++t) outp[t] *= inv;
}

// ======================================================================
// Sparsity pattern of the real-basis w3j (structural nonzeros).
// ======================================================================

struct E3 { unsigned char i, j, k; };

constexpr E3 PAT_P0[1]  = {{0,0,0}};
constexpr E3 PAT_P1[3]  = {{0,0,0},{1,1,0},{2,2,0}};
constexpr E3 PAT_P2[5]  = {{0,0,0},{1,1,0},{2,2,0},{3,3,0},{4,4,0}};
constexpr E3 PAT_P3[3]  = {{0,0,0},{0,1,1},{0,2,2}};
constexpr E3 PAT_P4[3]  = {{0,0,0},{1,0,1},{2,0,2}};
constexpr E3 PAT_P5[11] = {{1,2,1},{1,3,2},{1,1,0},{2,2,2},{0,2,0},{2,3,1},
                           {0,1,1},{2,4,2},{0,0,2},{2,0,0},{0,4,0}};
constexpr E3 PAT_P6[11] = {{2,1,1},{2,2,2},{2,0,0},{3,1,2},{1,1,0},{3,2,1},
                           {1,0,1},{4,2,2},{0,0,2},{4,0,0},{0,2,0}};
constexpr E3 PAT_P7[5]  = {{0,0,0},{0,1,1},{0,2,2},{0,3,3},{0,4,4}};
constexpr E3 PAT_P8[11] = {{1,1,2},{1,2,3},{1,0,1},{2,1,3},{0,1,1},{2,2,2},
                           {0,0,2},{2,2,4},{0,0,4},{2,0,0},{0,2,0}};
constexpr E3 PAT_P9[5]  = {{0,0,0},{1,0,1},{2,0,2},{3,0,3},{4,0,4}};
constexpr E3 PAT_P10[25]= {{2,2,2},{2,3,3},{2,1,1},{2,4,4},{2,0,0},{3,2,3},
                           {1,2,1},{3,3,2},{1,1,2},{3,3,4},{1,1,4},{3,1,0},
                           {1,3,0},{3,4,3},{1,0,3},{3,0,1},{1,4,1},{4,2,4},
                           {0,2,0},{4,3,3},{0,1,3},{4,1,1},{0,3,1},{4,4,2},
                           {0,0,2}};

constexpr int OFF_P[11] = {0, 1, 4, 9, 12, 15, 26, 37, 42, 53, 58};

struct W3JArg { float c[83]; };

static W3JArg build_w3j_sparse() {
    struct PD { const E3* pat; int ne; int l1, l2, lo; double alpha; };
    const double a0 = std::sqrt(1.0/3072.0), a1 = std::sqrt(3.0/4096.0),
                 a2 = std::sqrt(5.0/4096.0);
    const PD pd[11] = {
        {PAT_P0, 1, 0,0,0, a0}, {PAT_P1, 3, 1,1,0, a0}, {PAT_P2, 5, 2,2,0, a0},
        {PAT_P3, 3, 0,1,1, a1}, {PAT_P4, 3, 1,0,1, a1}, {PAT_P5,11, 1,2,1, a1},
        {PAT_P6,11, 2,1,1, a1}, {PAT_P7, 5, 0,2,2, a2}, {PAT_P8,11, 1,1,2, a2},
        {PAT_P9, 5, 2,0,2, a2}, {PAT_P10,25,2,2,2, a2}
    };
    W3JArg arg;
    for (int p = 0; p < 11; ++p) {
        double dense[125];
        wigner3j_dense(pd[p].l1, pd[p].l2, pd[p].lo, dense);
        int n2 = 2*pd[p].l2+1, n3 = 2*pd[p].lo+1;
        for (int e = 0; e < pd[p].ne; ++e) {
            const E3& t = pd[p].pat[e];
            arg.c[OFF_P[p] + e] =
                (float)(dense[(t.i * n2 + t.j) * n3 + t.k] * pd[p].alpha);
        }
    }
    return arg;
}

// ======================================================================
// Device
// ======================================================================

typedef __attribute__((ext_vector_type(8))) short short8;
typedef __attribute__((ext_vector_type(4))) float f32x4;

__device__ __forceinline__ unsigned pack2(float lo, float hi) {
    float2 f2; f2.x = lo; f2.y = hi;
    __hip_bfloat162 pk = __float22bfloat162_rn(f2);
    unsigned u; __builtin_memcpy(&u, &pk, 4); return u;
}

// One path: ca_e = c_e*a[i_e] once, then t0/t1 FMAs; pack + LDS store.
template<int NE, int A1, int A2, int D3, int SBASE, int SSTR>
__device__ __forceinline__ void do_path(const E3 (&pat)[NE],
                                        const float* __restrict__ cs,
                                        const float* a, const float* b0,
                                        const float* b1,
                                        unsigned* __restrict__ dst) {
    float ca[NE];
    #pragma unroll
    for (int e = 0; e < NE; ++e) ca[e] = cs[e] * a[A1 + pat[e].i];
    float t0[D3], t1[D3];
    #pragma unroll
    for (int k = 0; k < D3; ++k) { t0[k] = 0.0f; t1[k] = 0.0f; }
    #pragma unroll
    for (int e = 0; e < NE; ++e) {
        const int k = pat[e].k;
        t0[k] = fmaf(ca[e], b0[A2 + pat[e].j], t0[k]);
        t1[k] = fmaf(ca[e], b1[A2 + pat[e].j], t1[k]);
    }
    #pragma unroll
    for (int k = 0; k < D3; ++k)
        dst[(SBASE + k * SSTR) * 256] = pack2(t0[k], t1[k]);
}

__device__ __forceinline__ void build_all(const float* __restrict__ cs,
                                          const float* a, const float* b0,
                                          const float* b1,
                                          unsigned* __restrict__ dst) {
    do_path< 1,0,0,1, 0,1>(PAT_P0,  cs +  0, a, b0, b1, dst);
    do_path< 3,1,1,1, 1,1>(PAT_P1,  cs +  1, a, b0, b1, dst);
    do_path< 5,4,4,1, 2,1>(PAT_P2,  cs +  4, a, b0, b1, dst);
    do_path< 3,0,1,3, 3,4>(PAT_P3,  cs +  9, a, b0, b1, dst);
    do_path< 3,1,0,3, 4,4>(PAT_P4,  cs + 12, a, b0, b1, dst);
    do_path<11,1,4,3, 5,4>(PAT_P5,  cs + 15, a, b0, b1, dst);
    do_path<11,4,1,3, 6,4>(PAT_P6,  cs + 26, a, b0, b1, dst);
    do_path< 5,0,4,5,15,4>(PAT_P7,  cs + 37, a, b0, b1, dst);
    do_path<11,1,1,5,16,4>(PAT_P8,  cs + 42, a, b0, b1, dst);
    do_path< 5,4,0,5,17,4>(PAT_P9,  cs + 53, a, b0, b1, dst);
    do_path<25,4,4,5,18,4>(PAT_P10, cs + 58, a, b0, b1, dst);
}

__device__ __forceinline__ void load_a(const float* __restrict__ x1r, int u,
                                       float* a) {
    a[0] = x1r[u];
    #pragma unroll
    for (int i = 0; i < 3; ++i) a[1 + i] = x1r[32 + u * 3 + i];
    #pragma unroll
    for (int i = 0; i < 5; ++i) a[4 + i] = x1r[128 + u * 5 + i];
}

// B prefetch (fp32, direct from ws): 8 frags x 8 dwords.
// frag f -> path = pbase + (f>>1), nt = f&1; lane: w = (l&15)+nt*16,
// v = (l>>4)*8 + j.  addr = ((p*32+u)*32 + v)*32 + w.
__device__ __forceinline__ void load_b(const float* __restrict__ ws,
                                       int pbase, int u, int l,
                                       float (&bfr)[8][8]) {
    const int w_lo = l & 15, vb = (l >> 4) * 8;
    #pragma unroll
    for (int f = 0; f < 8; ++f) {
        const int p = pbase + (f >> 1);
        const int w = w_lo + (f & 1) * 16;
        const float* base = ws + (((size_t)(p * 32 + u) * 32 + vb) * 32 + w);
        #pragma unroll
        for (int j = 0; j < 8; ++j) bfr[f][j] = base[j * 32];
    }
}

__device__ __forceinline__ void cvt_frags(const float (&bfr)[8][8],
                                          short8 (&bf)[8]) {
    #pragma unroll
    for (int f = 0; f < 8; ++f) {
        unsigned tmp[4];
        #pragma unroll
        for (int j2 = 0; j2 < 4; ++j2)
            tmp[j2] = pack2(bfr[f][2 * j2], bfr[f][2 * j2 + 1]);
        __builtin_memcpy(&bf[f], tmp, 16);
    }
}

// ======================================================================
// Main kernel. Block 256 = 16 z x 16 v-pairs (build; b in regs for the
// whole kernel). Waves specialize by output irrep for MFMA:
//   wv0: io0 (slots 0-2, chain->1 acc per nt)
//   wv1: io1 (slots 3+kk*4+m, kk=0..2)
//   wv2: io2 kk=0,1 (slots 15+kk*4+m)
//   wv3: io2 kk=2,3,4
// Double-buffered shT -> exactly ONE __syncthreads per u-iteration.
// ======================================================================

#define SHT_WORDS (35 * 256)

__launch_bounds__(256, 2)
__global__ void tp_mfma(const float* __restrict__ x1,
                        const float* __restrict__ x2,
                        const float* __restrict__ ws,
                        float* __restrict__ out, W3JArg w3j) {
    __shared__ unsigned shT[2 * SHT_WORDS];

    const int tid = threadIdx.x;
    const int l = tid & 63, wv = tid >> 6;
    const int z0 = (blockIdx.x >> 2) * 16, u0 = (blockIdx.x & 3) * 8;
    const int tz = tid >> 4, vp = tid & 15, v0 = vp * 2;

    // ---- b0/b1 (x2 components for v0, v0+1) straight from global ----
    float b0[9], b1[9];
    {
        const float* xr = x2 + (size_t)(z0 + tz) * 288;
        float2 s0 = *(const float2*)(xr + v0);
        b0[0] = s0.x; b1[0] = s0.y;
        const float* p1 = xr + 32 + v0 * 3;     // 6 contiguous, 8B aligned
        float2 q0 = *(const float2*)(p1 + 0);
        float2 q1 = *(const float2*)(p1 + 2);
        float2 q2 = *(const float2*)(p1 + 4);
        b0[1] = q0.x; b0[2] = q0.y; b0[3] = q1.x;
        b1[1] = q1.y; b1[2] = q2.x; b1[3] = q2.y;
        const float* p2 = xr + 128 + v0 * 5;    // 10 contiguous, 8B aligned
        #pragma unroll
        for (int h = 0; h < 5; ++h) {
            float2 r = *(const float2*)(p2 + 2 * h);
            float vlo = r.x, vhi = r.y;
            // indices 2h, 2h+1 -> b0[4+idx] for idx<5 else b1[4+idx-5]
            if (2 * h < 5) b0[4 + 2 * h] = vlo; else b1[4 + 2 * h - 5] = vlo;
            if (2 * h + 1 < 5) b0[5 + 2 * h] = vhi; else b1[4 + 2 * h - 4] = vhi;
        }
    }

    const float* x1r = x1 + (size_t)(z0 + tz) * 288;
    const int pbase = (wv == 0) ? 0 : (wv == 1) ? 3 : 7;

    float a[2][9];
    load_a(x1r, u0, a[0]);

    float bfr[8][8];
    load_b(ws, pbase, u0, l, bfr);

    // swizzled LDS bases
    unsigned* dstbase = shT + tz * 16 + (vp & 3) + ((((vp >> 2) + (tz >> 1)) & 3) << 2);
    const unsigned* tb0 = shT + (l & 15) * 16 + ((((l >> 4) + ((l & 15) >> 1)) & 3) << 2);

    f32x4 acc[6];
    #pragma unroll
    for (int i = 0; i < 6; ++i) acc[i] = (f32x4)(0.0f);

    short8 bf[8];

    #pragma unroll 2
    for (int ui = 0; ui < 8; ++ui) {
        const int cur = ui & 1;
        // issue next a loads early (in flight during build)
        if (ui < 7) load_a(x1r, u0 + ui + 1, a[cur ^ 1]);

        build_all(w3j.c, a[cur], b0, b1, dstbase + cur * SHT_WORDS);
        cvt_frags(bfr, bf);

        __syncthreads();

        // issue next B loads (in flight during next build)
        if (ui < 7) load_b(ws, pbase, u0 + ui + 1, l, bfr);

        const unsigned* tb = tb0 + cur * SHT_WORDS;
        if (wv == 0) {
            #pragma unroll
            for (int m = 0; m < 3; ++m) {
                short8 af = *(const short8*)(tb + m * 256);
                acc[0] = __builtin_amdgcn_mfma_f32_16x16x32_bf16(af, bf[2*m+0], acc[0], 0, 0, 0);
                acc[1] = __builtin_amdgcn_mfma_f32_16x16x32_bf16(af, bf[2*m+1], acc[1], 0, 0, 0);
            }
        } else if (wv == 1) {
            #pragma unroll
            for (int kk = 0; kk < 3; ++kk)
                #pragma unroll
                for (int m = 0; m < 4; ++m) {
                    short8 af = *(const short8*)(tb + (3 + kk * 4 + m) * 256);
                    acc[2*kk+0] = __builtin_amdgcn_mfma_f32_16x16x32_bf16(af, bf[2*m+0], acc[2*kk+0], 0, 0, 0);
                    acc[2*kk+1] = __builtin_amdgcn_mfma_f32_16x16x32_bf16(af, bf[2*m+1], acc[2*kk+1], 0, 0, 0);
                }
        } else if (wv == 2) {
            #pragma unroll
            for (int kk = 0; kk < 2; ++kk)
                #pragma unroll
                for (int m = 0; m < 4; ++m) {
                    short8 af = *(const short8*)(tb + (15 + kk * 4 + m) * 256);
                    acc[2*kk+0] = __builtin_amdgcn_mfma_f32_16x16x32_bf16(af, bf[2*m+0], acc[2*kk+0], 0, 0, 0);
                    acc[2*kk+1] = __builtin_amdgcn_mfma_f32_16x16x32_bf16(af, bf[2*m+1], acc[2*kk+1], 0, 0, 0);
                }
        } else {
            #pragma unroll
            for (int kk = 2; kk < 5; ++kk)
                #pragma unroll
                for (int m = 0; m < 4; ++m) {
                    short8 af = *(const short8*)(tb + (15 + kk * 4 + m) * 256);
                    acc[2*(kk-2)+0] = __builtin_amdgcn_mfma_f32_16x16x32_bf16(af, bf[2*m+0], acc[2*(kk-2)+0], 0, 0, 0);
                    acc[2*(kk-2)+1] = __builtin_amdgcn_mfma_f32_16x16x32_bf16(af, bf[2*m+1], acc[2*(kk-2)+1], 0, 0, 0);
                }
        }
    }

    // ---- epilogue: D row = z0 + (l>>4)*4 + r, col = w (= l&15 + nt*16) ----
    const int zr = z0 + ((l >> 4) << 2);
    const int wl = l & 15;
    if (wv == 0) {
        #pragma unroll
        for (int nt = 0; nt < 2; ++nt) {
            const int w = wl + nt * 16;
            #pragma unroll
            for (int r = 0; r < 4; ++r)
                atomicAdd(&out[(size_t)(zr + r) * 288 + w], acc[nt][r]);
        }
    } else if (wv == 1) {
        #pragma unroll
        for (int kk = 0; kk < 3; ++kk)
            #pragma unroll
            for (int nt = 0; nt < 2; ++nt) {
                const int w = wl + nt * 16;
                #pragma unroll
                for (int r = 0; r < 4; ++r)
                    atomicAdd(&out[(size_t)(zr + r) * 288 + 32 + w * 3 + kk], acc[2*kk+nt][r]);
            }
    } else if (wv == 2) {
        #pragma unroll
        for (int kk = 0; kk < 2; ++kk)
            #pragma unroll
            for (int nt = 0; nt < 2; ++nt) {
                const int w = wl + nt * 16;
                #pragma unroll
                for (int r = 0; r < 4; ++r)
                    atomicAdd(&out[(size_t)(zr + r) * 288 + 128 + w * 5 + kk], acc[2*kk+nt][r]);
            }
    } else {
        #pragma unroll
        for (int kk = 2; kk < 5; ++kk)
            #pragma unroll
            for (int nt = 0; nt < 2; ++nt) {
                const int w = wl + nt * 16;
                #pragma unroll
                for (int r = 0; r < 4; ++r)
                    atomicAdd(&out[(size_t)(zr + r) * 288 + 128 + w * 5 + kk], acc[2*(kk-2)+nt][r]);
            }
    }
}

// ======================================================================

extern "C" void kernel_launch(void* const* d_in, const int* in_sizes, int n_in,
                              void* d_out, int out_size, void* d_ws, size_t ws_size,
                              hipStream_t stream) {
    const float* x1 = (const float*)d_in[0];
    const float* x2 = (const float*)d_in[1];
    const float* ws = (const float*)d_in[2];
    float* out = (float*)d_out;

    static const W3JArg arg = build_w3j_sparse();

    const int B = in_sizes[0] / 288;          // 2048
    const int grid = (B / 16) * 4;            // z-tiles x 4 u-groups

    hipMemsetAsync(out, 0, (size_t)out_size * sizeof(float), stream);
    tp_mfma<<<dim3(grid), dim3(256), 0, stream>>>(x1, x2, ws, out, arg);
}